// Round 6
// baseline (1077.707 us; speedup 1.0000x reference)
//
#include <hip/hip_runtime.h>
#include <hip/hip_bf16.h>

typedef __attribute__((ext_vector_type(8))) short short8;
typedef __attribute__((ext_vector_type(4))) float floatx4;
typedef __attribute__((ext_vector_type(2))) float f32x2;
typedef __attribute__((ext_vector_type(2))) int i32x2;
typedef unsigned short u16;

#define T_SZ 609
#define K1V  4872   // valid K of flattened LSTM output (609*8)
#define K1P  4896   // padded to multiple of 32

static __device__ __forceinline__ u16 f2bf(float f) {
    union { float f; unsigned u; } a; a.f = f;
    unsigned r = a.u + 0x7FFF + ((a.u >> 16) & 1);   // round-to-nearest-even
    return (u16)(r >> 16);
}

// async global->LDS, 16B per lane; LDS dest = wave-uniform base + lane*16
static __device__ __forceinline__ void gload_lds16(const u16* g, u16* l) {
    __builtin_amdgcn_global_load_lds(
        (const __attribute__((address_space(1))) void*)g,
        (__attribute__((address_space(3))) void*)l, 16, 0, 0);
}

// ==================== fp32 -> bf16 conversion (plain) ====================
__global__ __launch_bounds__(256) void cvt_kernel(const float* __restrict__ s,
                                                  u16* __restrict__ d, int n) {
    int i = (blockIdx.x * 256 + threadIdx.x) * 8;
    if (i < n) {
        float4 a = *(const float4*)(s + i);
        float4 b = *(const float4*)(s + i + 4);
        u16 o[8] = { f2bf(a.x), f2bf(a.y), f2bf(a.z), f2bf(a.w),
                     f2bf(b.x), f2bf(b.y), f2bf(b.z), f2bf(b.w) };
        *(uint4*)(d + i) = *(const uint4*)o;
    }
}

// ============== fp32 -> bf16 with row/col zero padding ==============
__global__ __launch_bounds__(256) void cvt_pad_kernel(const float* __restrict__ s,
                                                      u16* __restrict__ d,
                                                      int R, int K, int Kp) {
    int chunk = blockIdx.x * 256 + threadIdx.x;
    int cpr = Kp >> 3;
    int r = chunk / cpr;
    int c = (chunk - r * cpr) << 3;
    u16 o[8] = {0, 0, 0, 0, 0, 0, 0, 0};
    if (r < R && c < K) {
        const float* p = s + (size_t)r * K + c;
        float4 a = *(const float4*)p;
        float4 b = *(const float4*)(p + 4);
        o[0] = f2bf(a.x); o[1] = f2bf(a.y); o[2] = f2bf(a.z); o[3] = f2bf(a.w);
        o[4] = f2bf(b.x); o[5] = f2bf(b.y); o[6] = f2bf(b.z); o[7] = f2bf(b.w);
    }
    *(uint4*)&d[(size_t)r * Kp + c] = *(const uint4*)o;
}

// ============================ LSTM (K-split, 1 row/wave, zero DS ops) ============================
// One wave = ONE batch row. lane = hk*32 + grp*8 + j: hk selects the K-half of each
// gate dot (hk0 = recurrent Whh*h half (+bias), hk1 = input Wih*in half), grp = gate
// group in order [i, g~, f, o], j = hidden unit. Each lane does 4 pk-FMA per layer;
// per-lane weights = 24 floats + 3 biases -> trivially register-resident (ends the
// round-2/4/5 allocator fight). 2048 waves = 2 waves/SIMD -> in-order stalls of one
// wave are filled by the other.
// ALL cross-lane ops are VALU (no ds_swizzle -> no LDS-pipe latency on the chain):
//  - half-sum reduce:  v_permlane32_swap(a,a) -> r[0]+r[1] = a[lane&31]+a[lane|32]
//  - i*g~ / f combine: v_permlane16_swap(m,m) -> r[0]=even-16-row bcast (i*g~),
//    r[1]=odd-row bcast (f); cn = fma(r[1], cin, r[0]) on all 64 lanes, no cndmask
//  - h broadcast:      v_permlane16_swap(h,h) -> r[1] = valid h (from f/o rows)
//  - 8-wide butterfly: quad_perm/row_half_mirror DPPs (unchanged)
// Layer skew (L1 step t, L2 t-1, L3 t-2) keeps the three chains independent.

template<int CTRL>
static __device__ __forceinline__ float dppf(float v) {
    union { float f; int i; } a, b;
    a.f = v;
    b.i = __builtin_amdgcn_update_dpp(0, a.i, CTRL, 0xF, 0xF, true);
    return b.f;
}

// dual-output 16-row swap of a value with itself:
// ev = broadcast of even 16-rows (within each row pair), od = broadcast of odd rows
static __device__ __forceinline__ void pl16(float v, float& ev, float& od) {
    union { float f; int i; } a; a.f = v;
    i32x2 r = __builtin_amdgcn_permlane16_swap(a.i, a.i, false, false);
    union { int i; float f; } x, y; x.i = r.x; y.i = r.y;
    ev = x.f; od = y.f;
}

// xor-32 reduce: returns a[lane&31] + a[(lane&31)+32] on every lane
static __device__ __forceinline__ float red32(float v) {
    union { float f; int i; } a; a.f = v;
    i32x2 r = __builtin_amdgcn_permlane32_swap(a.i, a.i, false, false);
    union { int i; float f; } x, y; x.i = r.x; y.i = r.y;
    return x.f + y.f;
}

// anti-remat pins: make the value's def an opaque asm so the allocator must keep it
static __device__ __forceinline__ void pinv(f32x2& v) {
    float a = v.x, b = v.y;
    asm volatile("" : "+v"(a), "+v"(b));
    v = (f32x2){a, b};
}
static __device__ __forceinline__ void pinf(float& a) {
    asm volatile("" : "+v"(a));
}

// o[m].x = v[lane^(2m)], o[m].y = v[lane^(2m+1)]  (xors within each 8-lane group)
static __device__ __forceinline__ void bfly2(float v, f32x2* o) {
    o[0] = (f32x2){v,              dppf<0xB1>(v)};   // xor0, xor1 (quad_perm 1,0,3,2)
    o[1] = (f32x2){dppf<0x4E>(v),  dppf<0x1B>(v)};   // xor2, xor3
    float m7 = dppf<0x141>(v);                       // row_half_mirror = xor7
    o[2] = (f32x2){dppf<0x1B>(m7), dppf<0x4E>(m7)};  // xor4 (=7^3), xor5 (=7^2)
    o[3] = (f32x2){dppf<0xB1>(m7), m7};              // xor6 (=7^1), xor7
}

static __device__ __forceinline__ float dot8(const f32x2* w, const f32x2* v, float s0) {
    f32x2 acc = (f32x2){s0, 0.f};
#pragma unroll
    for (int m = 0; m < 4; ++m) acc = __builtin_elementwise_fma(w[m], v[m], acc);
    return acc.x + acc.y;
}

// tanh(x) = 2*sigmoid(2x) - 1  (saturates correctly at +/-inf)
static __device__ __forceinline__ float tns(float a) {
    return __builtin_fmaf(2.f, __fdividef(1.f, 1.f + __expf(-2.f * a)), -1.f);
}

__global__ __launch_bounds__(64, 2) void lstm3_kernel(
    const float* __restrict__ x,
    const float* __restrict__ Wih1, const float* __restrict__ Whh1,
    const float* __restrict__ bih1, const float* __restrict__ bhh1,
    const float* __restrict__ Wih2, const float* __restrict__ Whh2,
    const float* __restrict__ bih2, const float* __restrict__ bhh2,
    const float* __restrict__ Wih3, const float* __restrict__ Whh3,
    const float* __restrict__ bih3, const float* __restrict__ bhh3,
    u16* __restrict__ A1)
{
    const int lane = threadIdx.x & 63;
    const int hk   = lane >> 5;          // K-half: 0 = recurrent, 1 = input
    const int gj   = lane & 31;
    const int grp  = gj >> 3;            // 0:i 1:g~ 2:f 3:o
    const int j    = gj & 7;             // hidden unit
    const int row  = blockIdx.x;         // ONE batch row per wave

    // zero the K padding columns of A1 (ws is poisoned each launch): 24 cols
    if (threadIdx.x < 24) {
        A1[(size_t)row * K1P + K1V + threadIdx.x] = 0;
    }

    const int ptg = (grp == 1) ? 2 : ((grp == 2) ? 1 : grp);   // grp -> PyTorch gate
    const int G   = ptg * 8 + j;         // row in the 4H weight matrices

    // per-lane weights in butterfly order: slot (m,comp) multiplies in[j^(2m+comp)].
    // hk0 lanes hold Whh (+bias); hk1 lanes hold Wih (x zero-padded past 5 for L1).
    f32x2 w1[4], w2[4], w3[4];
#pragma unroll
    for (int m = 0; m < 4; ++m) {
        const int ka = j ^ (2 * m), kb = ka ^ 1;
        w1[m] = hk ? (f32x2){(ka < 5) ? Wih1[G * 5 + ka] : 0.f,
                             (kb < 5) ? Wih1[G * 5 + kb] : 0.f}
                   : (f32x2){Whh1[G * 8 + ka], Whh1[G * 8 + kb]};
        w2[m] = hk ? (f32x2){Wih2[G * 8 + ka], Wih2[G * 8 + kb]}
                   : (f32x2){Whh2[G * 8 + ka], Whh2[G * 8 + kb]};
        w3[m] = hk ? (f32x2){Wih3[G * 8 + ka], Wih3[G * 8 + kb]}
                   : (f32x2){Whh3[G * 8 + ka], Whh3[G * 8 + kb]};
    }
    float bs1 = hk ? 0.f : bih1[G] + bhh1[G];
    float bs2 = hk ? 0.f : bih2[G] + bhh2[G];
    float bs3 = hk ? 0.f : bih3[G] + bhh3[G];

#pragma unroll
    for (int m = 0; m < 4; ++m) { pinv(w1[m]); pinv(w2[m]); pinv(w3[m]); }
    pinf(bs1); pinf(bs2); pinf(bs3);

    // branchless activation constants: sigmoid for i/f/o, tanh (=2*sigm(2x)-1) for g~
    const float am = (grp == 1) ? -2.f : -1.f;
    const float aa = (grp == 1) ?  2.f :  1.f;
    const float ab = (grp == 1) ? -1.f :  0.f;
    const bool  isf = (grp == 2);

    // layer finish: gate preact (replicated all lanes) -> (c,h); h valid on ALL lanes
    auto lfin = [&](float a, float cin, float& cout) -> float {
        float e  = __expf(am * a);
        float v  = __builtin_fmaf(aa, __fdividef(1.f, 1.f + e), ab);
        float w1_ = dppf<0x128>(v);              // row_ror:8 = xor8 within 16-lane row
        float ig = v * w1_;                      // even rows: i*g~
        float fv = isf ? v : w1_;                // odd rows: f
        float m  = (lane & 16) ? fv : ig;
        float igA, ffA; pl16(m, igA, ffA);       // igA = i*g~ bcast, ffA = f bcast
        float cn = __builtin_fmaf(ffA, cin, igA);
        cout = cn;
        float th = tns(cn);
        float ov = isf ? w1_ : v;                // odd rows: o
        float h  = ov * th;
        float he, ho; pl16(h, he, ho);           // ho = valid h bcast (from odd rows)
        return ho;
    };

    const float* xrow = x + (size_t)row * (T_SZ * 5);
    const int jx = (j < 5) ? j : 0;      // lanes j>=5 load a valid addr; their slots
                                         // hit zero weights
    u16* outp = A1 + (size_t)row * K1P;

    float h1s = 0.f, h2s = 0.f, h3s = 0.f;   // h for own unit j, replicated
    float c1 = 0.f, c2 = 0.f, c3 = 0.f;
    float xc = xrow[jx];                 // x(t=0)

#pragma unroll 1
    for (int t = 0; t < T_SZ + 2; ++t) {
        const int tn = (t + 1 < T_SZ) ? t + 1 : T_SZ - 1;
        const float xn = xrow[tn * 5 + jx];      // prefetch next step's x (clamped)
        const bool s2 = (t >= 1), s3 = (t >= 2);

        // butterfly the dot inputs; hk selects which operand this half multiplies.
        // a1: hk0 Whh1*h1(t-1) | hk1 Wih1*x(t)
        // a2: hk0 Whh2*h2(t-2) | hk1 Wih2*h1(t-1)
        // a3: hk0 Whh3*h3(t-3) | hk1 Wih3*h2(t-2)
        f32x2 u1[4], u2[4], u3[4];
        bfly2(hk ? xc  : h1s, u1);
        bfly2(hk ? h1s : h2s, u2);
        bfly2(hk ? h2s : h3s, u3);
        float a1 = red32(dot8(w1, u1, bs1));
        float a2 = red32(dot8(w2, u2, bs2));
        float a3 = red32(dot8(w3, u3, bs3));

        // ---------------- L1 finish (step t) ----------------
        float c1n; float h1n = lfin(a1, c1, c1n); c1 = c1n;
        // ---------------- L2 finish (step t-1; masked for t==0) ----------------
        float c2n; float h2n = lfin(a2, c2, c2n);
        c2 = s2 ? c2n : 0.f; h2n = s2 ? h2n : 0.f;
        // ---------------- L3 finish (step t-2; masked for t<2) ----------------
        float c3n; float h3n = lfin(a3, c3, c3n);
        c3 = s3 ? c3n : 0.f; h3n = s3 ? h3n : 0.f;

        if (s3 && hk == 0 && grp == 0) outp[(t - 2) * 8 + j] = f2bf(h3n);

        h1s = h1n; h2s = h2n; h3s = h3n; xc = xn;
    }
}

// ============================ bf16 NT GEMM + bias + (ReLU) ============================
// C[m][n] = act( sum_k A[m][k]*B[n][k] + bias[n] ). 16x16x32 bf16 MFMA, BK=32,
// m97-style async staging: global_load_lds dwordx4, unpadded LDS (row = 32 u16).
template<int BM, int BN, bool RELU, bool NGUARD, bool OUTF32>
__global__ __launch_bounds__(256) void gemm_bt(
    const u16* __restrict__ A, int lda,
    const u16* __restrict__ B, int ldb,
    const float* __restrict__ bias,
    void* __restrict__ Cv, int ldc, int N, int K)
{
    constexpr int WM = BM / 2, WN = BN / 2;
    constexpr int TM = WM / 16, TN = WN / 16;
    __shared__ u16 As[BM * 32];
    __shared__ u16 Bs[BN * 32];

    const int tid = threadIdx.x;
    const int bm  = blockIdx.y * BM;
    const int bn  = blockIdx.x * BN;
    const int l   = tid & 63, w = tid >> 6;
    const int wr  = w >> 1, wc = w & 1;
    const int lr  = l & 15, q = l >> 4;
    const int lrow = l >> 2;            // staging: lane -> row within 16-row group
    const int lcol = (l & 3) << 3;      // staging: lane -> 8-elem chunk

    floatx4 acc[TM][TN];
#pragma unroll
    for (int i = 0; i < TM; ++i)
#pragma unroll
        for (int j = 0; j < TN; ++j) acc[i][j] = (floatx4){0.f, 0.f, 0.f, 0.f};

    const u16* Ab = A + (size_t)bm * lda;
    const u16* Bb = B + (size_t)bn * ldb;

    for (int k0 = 0; k0 < K; k0 += 32) {
#pragma unroll
        for (int i = 0; i < BM / 64; ++i) {
            int r0 = w * (BM / 4) + i * 16;
            gload_lds16(Ab + (size_t)(r0 + lrow) * lda + k0 + lcol, &As[r0 * 32]);
        }
#pragma unroll
        for (int i = 0; i < BN / 64; ++i) {
            int r0 = w * (BN / 4) + i * 16;
            gload_lds16(Bb + (size_t)(r0 + lrow) * ldb + k0 + lcol, &Bs[r0 * 32]);
        }
        __syncthreads();

        short8 fa[TM], fb[TN];
#pragma unroll
        for (int i = 0; i < TM; ++i)
            fa[i] = *(const short8*)&As[(wr * WM + i * 16 + lr) * 32 + q * 8];
#pragma unroll
        for (int j = 0; j < TN; ++j)
            fb[j] = *(const short8*)&Bs[(wc * WN + j * 16 + lr) * 32 + q * 8];
#pragma unroll
        for (int i = 0; i < TM; ++i)
#pragma unroll
            for (int j = 0; j < TN; ++j)
                acc[i][j] = __builtin_amdgcn_mfma_f32_16x16x32_bf16(fa[i], fb[j], acc[i][j], 0, 0, 0);
        __syncthreads();
    }

    // epilogue: C/D layout col = lane&15, row = (lane>>4)*4 + reg  [m89/m91]
#pragma unroll
    for (int j = 0; j < TN; ++j) {
        int n = bn + wc * WN + j * 16 + lr;
        bool nok = (!NGUARD) || (n < N);
        float bv = nok ? bias[n] : 0.f;
#pragma unroll
        for (int i = 0; i < TM; ++i) {
            int m0r = bm + wr * WM + i * 16 + q * 4;
#pragma unroll
            for (int r = 0; r < 4; ++r) {
                float vv = acc[i][j][r] + bv;
                if (RELU) vv = fmaxf(vv, 0.f);
                if (nok) {
                    size_t idx = (size_t)(m0r + r) * ldc + n;
                    if (OUTF32) ((float*)Cv)[idx] = vv;
                    else        ((u16*)Cv)[idx] = f2bf(vv);
                }
            }
        }
    }
}

// ============================ launch ============================
extern "C" void kernel_launch(void* const* d_in, const int* in_sizes, int n_in,
                              void* d_out, int out_size, void* d_ws, size_t ws_size,
                              hipStream_t stream)
{
    const float* x    = (const float*)d_in[0];
    const float* Wih1 = (const float*)d_in[1];
    const float* Whh1 = (const float*)d_in[2];
    const float* bih1 = (const float*)d_in[3];
    const float* bhh1 = (const float*)d_in[4];
    const float* Wih2 = (const float*)d_in[5];
    const float* Whh2 = (const float*)d_in[6];
    const float* bih2 = (const float*)d_in[7];
    const float* bhh2 = (const float*)d_in[8];
    const float* Wih3 = (const float*)d_in[9];
    const float* Whh3 = (const float*)d_in[10];
    const float* bih3 = (const float*)d_in[11];
    const float* bhh3 = (const float*)d_in[12];
    const float* W1 = (const float*)d_in[13];
    const float* b1 = (const float*)d_in[14];
    const float* W2 = (const float*)d_in[15];
    const float* b2 = (const float*)d_in[16];
    const float* W3 = (const float*)d_in[17];
    const float* b3 = (const float*)d_in[18];

    // ws layout (bf16 elems): A1[2048][4896], A2[2048][4096], A3[2048][1024],
    // W1b[4096][4896] (K-padded), W2b[1024][4096], W3b[640][1024] (row-padded). ~91 MB.
    u16* A1  = (u16*)d_ws;
    u16* A2  = A1  + (size_t)2048 * K1P;
    u16* A3  = A2  + (size_t)2048 * 4096;
    u16* W1b = A3  + (size_t)2048 * 1024;
    u16* W2b = W1b + (size_t)4096 * K1P;
    u16* W3b = W2b + (size_t)1024 * 4096;

    // weight conversions fp32 -> bf16 (zero-padded where needed)
    cvt_pad_kernel<<<9792, 256, 0, stream>>>(W1, W1b, 4096, K1V, K1P);
    cvt_kernel<<<2048, 256, 0, stream>>>(W2, W2b, 1024 * 4096);
    cvt_pad_kernel<<<320, 256, 0, stream>>>(W3, W3b, T_SZ, 1024, 1024);

    // LSTM: 1 row/wave K-split, 2048 waves = 2 per SIMD, zero DS ops
    lstm3_kernel<<<2048, 64, 0, stream>>>(x, Wih1, Whh1, bih1, bhh1,
                                          Wih2, Whh2, bih2, bhh2,
                                          Wih3, Whh3, bih3, bhh3, A1);

    // L1: [2048,4896] x W1b[4096,4896] -> relu -> A2 [2048,4096]  (bf16 out)
    gemm_bt<128, 128, true, false, false><<<dim3(32, 16), 256, 0, stream>>>(
        A1, K1P, W1b, K1P, b1, A2, 4096, 4096, K1P);

    // L2: [2048,4096] x W2b[1024,4096] -> relu -> A3 [2048,1024]  (bf16 out)
    gemm_bt<64, 128, true, false, false><<<dim3(8, 32), 256, 0, stream>>>(
        A2, 4096, W2b, 4096, b2, A3, 1024, 1024, 4096);

    // L3: [2048,1024] x W3b[640,1024] -> d_out [2048,609]  (fp32 out, store N-guard)
    gemm_bt<64, 128, false, true, true><<<dim3(5, 32), 256, 0, stream>>>(
        A3, 1024, W3b, 1024, b3, d_out, T_SZ, T_SZ, 1024);
}

// Round 7
// 684.896 us; speedup vs baseline: 1.5735x; 1.5735x over previous
//
#include <hip/hip_runtime.h>
#include <hip/hip_bf16.h>

typedef __attribute__((ext_vector_type(8))) short short8;
typedef __attribute__((ext_vector_type(4))) float floatx4;
typedef __attribute__((ext_vector_type(2))) float f32x2;
typedef __attribute__((ext_vector_type(2))) int i32x2;
typedef unsigned short u16;

#define T_SZ 609
#define K1V  4872   // valid K of flattened LSTM output (609*8)
#define K1P  4896   // padded to multiple of 32
#define RD   16     // LDS ring depth (slots)

static __device__ __forceinline__ u16 f2bf(float f) {
    union { float f; unsigned u; } a; a.f = f;
    unsigned r = a.u + 0x7FFF + ((a.u >> 16) & 1);   // round-to-nearest-even
    return (u16)(r >> 16);
}

// async global->LDS, 16B per lane; LDS dest = wave-uniform base + lane*16
static __device__ __forceinline__ void gload_lds16(const u16* g, u16* l) {
    __builtin_amdgcn_global_load_lds(
        (const __attribute__((address_space(1))) void*)g,
        (__attribute__((address_space(3))) void*)l, 16, 0, 0);
}

#define WG_LOAD(p)     __hip_atomic_load((p), __ATOMIC_ACQUIRE, __HIP_MEMORY_SCOPE_WORKGROUP)
#define WG_STORE(p, v) __hip_atomic_store((p), (v), __ATOMIC_RELEASE, __HIP_MEMORY_SCOPE_WORKGROUP)

// ===================== cross-lane primitives (all HW-verified this session) =====================
template<int CTRL>
static __device__ __forceinline__ float dppf(float v) {
    union { float f; int i; } a, b;
    a.f = v;
    b.i = __builtin_amdgcn_update_dpp(0, a.i, CTRL, 0xF, 0xF, true);
    return b.f;
}

// dual-output 16-row swap of a value with itself (verified round 6)
static __device__ __forceinline__ void pl16(float v, float& ev, float& od) {
    union { float f; int i; } a; a.f = v;
    i32x2 r = __builtin_amdgcn_permlane16_swap(a.i, a.i, false, false);
    union { int i; float f; } x, y; x.i = r.x; y.i = r.y;
    ev = x.f; od = y.f;
}

// o[m].x = v[lane^(2m)], o[m].y = v[lane^(2m+1)]  (xors within each 8-lane group)
static __device__ __forceinline__ void bfly2(float v, f32x2* o) {
    o[0] = (f32x2){v,              dppf<0xB1>(v)};   // xor0, xor1 (quad_perm 1,0,3,2)
    o[1] = (f32x2){dppf<0x4E>(v),  dppf<0x1B>(v)};   // xor2, xor3
    float m7 = dppf<0x141>(v);                       // row_half_mirror = xor7
    o[2] = (f32x2){dppf<0x1B>(m7), dppf<0x4E>(m7)};  // xor4 (=7^3), xor5 (=7^2)
    o[3] = (f32x2){dppf<0xB1>(m7), m7};              // xor6 (=7^1), xor7
}

// tanh(x) = 2*sigmoid(2x) - 1  (saturates correctly at +/-inf)
static __device__ __forceinline__ float tns(float a) {
    return __builtin_fmaf(2.f, __fdividef(1.f, 1.f + __expf(-2.f * a)), -1.f);
}

static __device__ __forceinline__ void cvt8(const float* __restrict__ p, u16* __restrict__ d) {
    float4 a = *(const float4*)p;
    float4 b = *(const float4*)(p + 4);
    u16 o[8] = { f2bf(a.x), f2bf(a.y), f2bf(a.z), f2bf(a.w),
                 f2bf(b.x), f2bf(b.y), f2bf(b.z), f2bf(b.w) };
    *(uint4*)d = *(const uint4*)o;
}
static __device__ __forceinline__ void zero8(u16* __restrict__ d) {
    *(uint4*)d = (uint4){0, 0, 0, 0};
}

// ============================ LSTM (3-wave pipeline v2) + fused weight cvt ============================
// Blocks 0..1023: round-0's PROVEN 3-wave/2-row pipeline (wave w = layer w, 338 us
// measured), upgraded:
//  - lstep's 4 ds_bpermute (__shfl, ~120cy LDS pipe) -> round-6's lfin: xor8 DPP +
//    2x permlane16_swap, pure VALU, HW-verified round 6. Gate lane order [i,g~,f,o].
//  - own-recurrence h now lives in registers on all lanes -> recurrent dot via bfly2
//    (7 DPP) + butterfly-ordered Whh. r3 ring and all own-ring ds_reads deleted.
//  - quad handshake: RD=16 ring, polls+releases once per 4 steps, upstream h
//    prefetched 1 step ahead (covered by the quad poll) -> ds_read off the chain.
//    Bounds: producer <= consumer+12 < 16 slots; poll targets 4-aligned to match
//    release points; forced releases at t=T-1.
// Blocks 1024..1279: fp32->bf16 weight conversion (W1b/W2b/W3b), grid-stride.
// Independent memory-bound work overlapping the latency-bound LSTM waves.
__global__ __launch_bounds__(192) void lstm3_fused(
    const float* __restrict__ x,
    const float* __restrict__ Wih1, const float* __restrict__ Whh1,
    const float* __restrict__ bih1, const float* __restrict__ bhh1,
    const float* __restrict__ Wih2, const float* __restrict__ Whh2,
    const float* __restrict__ bih2, const float* __restrict__ bhh2,
    const float* __restrict__ Wih3, const float* __restrict__ Whh3,
    const float* __restrict__ bih3, const float* __restrict__ bhh3,
    u16* __restrict__ A1,
    const float* __restrict__ W1, u16* __restrict__ W1b,
    const float* __restrict__ W2, u16* __restrict__ W2b,
    const float* __restrict__ W3, u16* __restrict__ W3b)
{
    // ---------------- cvt role ----------------
    if (blockIdx.x >= 1024) {
        const int ct = (blockIdx.x - 1024) * 192 + threadIdx.x;
        const int cs = 256 * 192;
        for (int i = ct; i < 4096 * 612; i += cs) {          // W1: 4096 x 4896 (K pad)
            int r = i / 612, c = (i - r * 612) << 3;
            u16* d = W1b + (size_t)r * K1P + c;
            if (c < K1V) cvt8(W1 + (size_t)r * K1V + c, d); else zero8(d);
        }
        for (int i = ct; i < 524288; i += cs)                // W2: 1024 x 4096
            cvt8(W2 + (size_t)i * 8, W2b + (size_t)i * 8);
        for (int i = ct; i < 640 * 128; i += cs) {           // W3: 609 x 1024 -> 640 rows
            int r = i >> 7, c = (i & 127) << 3;
            u16* d = W3b + (size_t)r * 1024 + c;
            if (r < T_SZ) cvt8(W3 + (size_t)r * 1024 + c, d); else zero8(d);
        }
        return;
    }

    // ---------------- LSTM role ----------------
    __shared__ __align__(16) float xs[2 * T_SZ * 5];          // 24,360 B
    __shared__ __align__(16) float r1[RD * 16], r2[RD * 16];  // 1 KB each
    __shared__ int p1, p2, c2, c3;

    const int tid = threadIdx.x;
    const int b0  = blockIdx.x * 2;

    const float* xg = x + (size_t)b0 * (T_SZ * 5);
    for (int i = tid; i < 2 * T_SZ * 5; i += 192) xs[i] = xg[i];
    if (tid == 0) { p1 = 0; p2 = 0; c2 = 0; c3 = 0; }
    // zero the K padding columns of A1 (ws is poisoned each launch): 2 rows x 24 cols
    if (tid < 48) {
        int rr = tid / 24, cc = tid - rr * 24;
        A1[(size_t)(b0 + rr) * K1P + K1V + cc] = 0;
    }
    __syncthreads();

    const int lane = tid & 63, wid = tid >> 6;
    const int rh   = lane >> 5;          // row within block (0/1)
    const int gj   = lane & 31;
    const int grp  = gj >> 3;            // 0:i 1:g~ 2:f 3:o
    const int j    = gj & 7;             // hidden unit
    const int ptg  = (grp == 1) ? 2 : ((grp == 2) ? 1 : grp);   // grp -> PyTorch gate
    const int G    = ptg * 8 + j;        // row in the 4H weight matrices

    // branchless activation constants: sigmoid for i/f/o, tanh (=2*sigm(2x)-1) for g~
    const float am = (grp == 1) ? -2.f : -1.f;
    const float aa = (grp == 1) ?  2.f :  1.f;
    const float ab = (grp == 1) ? -1.f :  0.f;
    const bool  isf = (grp == 2);

    // layer finish: gate preact -> (c,h); h returned valid on ALL lanes.
    // VERBATIM round-6 lfin (HW-verified): per-16-row ops, both rh halves independent.
    auto lfin = [&](float a, float cin, float& cout) -> float {
        float e   = __expf(am * a);
        float v   = __builtin_fmaf(aa, __fdividef(1.f, 1.f + e), ab);
        float w1_ = dppf<0x128>(v);              // row_ror:8 = xor8 within 16-lane row
        float ig  = v * w1_;                     // low 16: i*g~
        float fv  = isf ? v : w1_;               // high 16: f
        float m   = (lane & 16) ? fv : ig;
        float igA, ffA; pl16(m, igA, ffA);
        float cn  = __builtin_fmaf(ffA, cin, igA);   // replicated on all lanes
        cout = cn;
        float th  = tns(cn);
        float ov  = isf ? w1_ : v;               // high 16: o
        float h   = ov * th;
        float he, ho; pl16(h, he, ho);           // ho = valid h bcast
        return ho;
    };

    if (wid == 0) {
        // ---------------- L1 wave (producer of r1/p1, throttled by c2) ----------------
        float wi5[5]; f32x2 whbf[4];
#pragma unroll
        for (int k = 0; k < 5; ++k) wi5[k] = Wih1[G * 5 + k];
#pragma unroll
        for (int m = 0; m < 4; ++m) {
            int ka = j ^ (2 * m), kb = ka ^ 1;
            whbf[m] = (f32x2){Whh1[G * 8 + ka], Whh1[G * 8 + kb]};
        }
        const float bs = bih1[G] + bhh1[G];
        const float* xr = &xs[rh * (T_SZ * 5)];
        float xc[5];
#pragma unroll
        for (int k = 0; k < 5; ++k) xc[k] = xr[k];
        float h1r = 0.f, c1s = 0.f;
#pragma unroll 1
        for (int t = 0; t < T_SZ; ++t) {
            if ((t & 3) == 0) while (WG_LOAD(&c2) < t - 8) {}
            float a = bs;
#pragma unroll
            for (int k = 0; k < 5; ++k) a = __builtin_fmaf(wi5[k], xc[k], a);
            f32x2 u[4]; bfly2(h1r, u);
            f32x2 B = (f32x2){0.f, 0.f};
#pragma unroll
            for (int m = 0; m < 4; ++m) B = __builtin_elementwise_fma(whbf[m], u[m], B);
            a += B.x + B.y;
            float cn; float hn = lfin(a, c1s, cn); c1s = cn; h1r = hn;
            if (grp == 0) r1[(t & (RD - 1)) * 16 + rh * 8 + j] = hn;
            if (lane == 0 && (((t & 3) == 3) || t == T_SZ - 1)) WG_STORE(&p1, t + 1);
            int tn = (t + 1 < T_SZ) ? t + 1 : T_SZ - 1;
#pragma unroll
            for (int k = 0; k < 5; ++k) xc[k] = xr[tn * 5 + k];   // prefetch next x
        }
    } else if (wid == 1) {
        // ---------------- L2 wave (consumer of r1, producer of r2, throttled by c3) ----------------
        f32x2 win[4], whbf[4];
#pragma unroll
        for (int m = 0; m < 4; ++m) {
            int ka = j ^ (2 * m), kb = ka ^ 1;
            win[m]  = (f32x2){Wih2[G * 8 + 2 * m], Wih2[G * 8 + 2 * m + 1]};
            whbf[m] = (f32x2){Whh2[G * 8 + ka],    Whh2[G * 8 + kb]};
        }
        const float bs = bih2[G] + bhh2[G];
        while (WG_LOAD(&p1) < 4) {}
        f32x2 hp[4];
        { const f32x2* s = (const f32x2*)&r1[rh * 8];
          hp[0] = s[0]; hp[1] = s[1]; hp[2] = s[2]; hp[3] = s[3]; }
        float h2r = 0.f, c2s = 0.f;
#pragma unroll 1
        for (int t = 0; t < T_SZ; ++t) {
            if ((t & 3) == 0 && t) {
                int need = (t + 4 < T_SZ) ? t + 4 : T_SZ;
                while (WG_LOAD(&p1) < need) {}
                while (WG_LOAD(&c3) < t - 8) {}
                const f32x2* s = (const f32x2*)&r1[(t & (RD - 1)) * 16 + rh * 8];
                hp[0] = s[0]; hp[1] = s[1]; hp[2] = s[2]; hp[3] = s[3];
            }
            f32x2 A = (f32x2){bs, 0.f};
#pragma unroll
            for (int m = 0; m < 4; ++m) A = __builtin_elementwise_fma(win[m], hp[m], A);
            f32x2 u[4]; bfly2(h2r, u);
            f32x2 B = (f32x2){0.f, 0.f};
#pragma unroll
            for (int m = 0; m < 4; ++m) B = __builtin_elementwise_fma(whbf[m], u[m], B);
            float a = A.x + A.y + B.x + B.y;
            float cn; float hn = lfin(a, c2s, cn); c2s = cn; h2r = hn;
            if (grp == 0) r2[(t & (RD - 1)) * 16 + rh * 8 + j] = hn;
            if (lane == 0 && (((t & 3) == 3) || t == T_SZ - 1)) {
                WG_STORE(&c2, t + 1);
                WG_STORE(&p2, t + 1);
            }
            if ((t & 3) != 3) {          // prefetch next upstream h (covered by quad poll)
                const f32x2* s = (const f32x2*)&r1[((t + 1) & (RD - 1)) * 16 + rh * 8];
                hp[0] = s[0]; hp[1] = s[1]; hp[2] = s[2]; hp[3] = s[3];
            }
        }
    } else {
        // ---------------- L3 wave (consumer of r2, writes A1) ----------------
        f32x2 win[4], whbf[4];
#pragma unroll
        for (int m = 0; m < 4; ++m) {
            int ka = j ^ (2 * m), kb = ka ^ 1;
            win[m]  = (f32x2){Wih3[G * 8 + 2 * m], Wih3[G * 8 + 2 * m + 1]};
            whbf[m] = (f32x2){Whh3[G * 8 + ka],    Whh3[G * 8 + kb]};
        }
        const float bs = bih3[G] + bhh3[G];
        u16* outp = A1 + (size_t)(b0 + rh) * K1P;
        while (WG_LOAD(&p2) < 4) {}
        f32x2 hp[4];
        { const f32x2* s = (const f32x2*)&r2[rh * 8];
          hp[0] = s[0]; hp[1] = s[1]; hp[2] = s[2]; hp[3] = s[3]; }
        float h3r = 0.f, c3s = 0.f;
#pragma unroll 1
        for (int t = 0; t < T_SZ; ++t) {
            if ((t & 3) == 0 && t) {
                int need = (t + 4 < T_SZ) ? t + 4 : T_SZ;
                while (WG_LOAD(&p2) < need) {}
                const f32x2* s = (const f32x2*)&r2[(t & (RD - 1)) * 16 + rh * 8];
                hp[0] = s[0]; hp[1] = s[1]; hp[2] = s[2]; hp[3] = s[3];
            }
            f32x2 A = (f32x2){bs, 0.f};
#pragma unroll
            for (int m = 0; m < 4; ++m) A = __builtin_elementwise_fma(win[m], hp[m], A);
            f32x2 u[4]; bfly2(h3r, u);
            f32x2 B = (f32x2){0.f, 0.f};
#pragma unroll
            for (int m = 0; m < 4; ++m) B = __builtin_elementwise_fma(whbf[m], u[m], B);
            float a = A.x + A.y + B.x + B.y;
            float cn; float hn = lfin(a, c3s, cn); c3s = cn; h3r = hn;
            if (grp == 0) outp[t * 8 + j] = f2bf(hn);
            if (lane == 0 && (((t & 3) == 3) || t == T_SZ - 1)) WG_STORE(&c3, t + 1);
            if ((t & 3) != 3) {
                const f32x2* s = (const f32x2*)&r2[((t + 1) & (RD - 1)) * 16 + rh * 8];
                hp[0] = s[0]; hp[1] = s[1]; hp[2] = s[2]; hp[3] = s[3];
            }
        }
    }
}

// ============================ bf16 NT GEMM + bias + (ReLU) ============================
// C[m][n] = act( sum_k A[m][k]*B[n][k] + bias[n] ). 16x16x32 bf16 MFMA, BK=32,
// m97-style async staging: global_load_lds dwordx4, unpadded LDS (row = 32 u16).
template<int BM, int BN, bool RELU, bool NGUARD, bool OUTF32>
__global__ __launch_bounds__(256) void gemm_bt(
    const u16* __restrict__ A, int lda,
    const u16* __restrict__ B, int ldb,
    const float* __restrict__ bias,
    void* __restrict__ Cv, int ldc, int N, int K)
{
    constexpr int WM = BM / 2, WN = BN / 2;
    constexpr int TM = WM / 16, TN = WN / 16;
    __shared__ u16 As[BM * 32];
    __shared__ u16 Bs[BN * 32];

    const int tid = threadIdx.x;
    const int bm  = blockIdx.y * BM;
    const int bn  = blockIdx.x * BN;
    const int l   = tid & 63, w = tid >> 6;
    const int wr  = w >> 1, wc = w & 1;
    const int lr  = l & 15, q = l >> 4;
    const int lrow = l >> 2;            // staging: lane -> row within 16-row group
    const int lcol = (l & 3) << 3;      // staging: lane -> 8-elem chunk

    floatx4 acc[TM][TN];
#pragma unroll
    for (int i = 0; i < TM; ++i)
#pragma unroll
        for (int j = 0; j < TN; ++j) acc[i][j] = (floatx4){0.f, 0.f, 0.f, 0.f};

    const u16* Ab = A + (size_t)bm * lda;
    const u16* Bb = B + (size_t)bn * ldb;

    for (int k0 = 0; k0 < K; k0 += 32) {
#pragma unroll
        for (int i = 0; i < BM / 64; ++i) {
            int r0 = w * (BM / 4) + i * 16;
            gload_lds16(Ab + (size_t)(r0 + lrow) * lda + k0 + lcol, &As[r0 * 32]);
        }
#pragma unroll
        for (int i = 0; i < BN / 64; ++i) {
            int r0 = w * (BN / 4) + i * 16;
            gload_lds16(Bb + (size_t)(r0 + lrow) * ldb + k0 + lcol, &Bs[r0 * 32]);
        }
        __syncthreads();

        short8 fa[TM], fb[TN];
#pragma unroll
        for (int i = 0; i < TM; ++i)
            fa[i] = *(const short8*)&As[(wr * WM + i * 16 + lr) * 32 + q * 8];
#pragma unroll
        for (int j = 0; j < TN; ++j)
            fb[j] = *(const short8*)&Bs[(wc * WN + j * 16 + lr) * 32 + q * 8];
#pragma unroll
        for (int i = 0; i < TM; ++i)
#pragma unroll
            for (int j = 0; j < TN; ++j)
                acc[i][j] = __builtin_amdgcn_mfma_f32_16x16x32_bf16(fa[i], fb[j], acc[i][j], 0, 0, 0);
        __syncthreads();
    }

    // epilogue: C/D layout col = lane&15, row = (lane>>4)*4 + reg  [m89/m91]
#pragma unroll
    for (int j = 0; j < TN; ++j) {
        int n = bn + wc * WN + j * 16 + lr;
        bool nok = (!NGUARD) || (n < N);
        float bv = nok ? bias[n] : 0.f;
#pragma unroll
        for (int i = 0; i < TM; ++i) {
            int m0r = bm + wr * WM + i * 16 + q * 4;
#pragma unroll
            for (int r = 0; r < 4; ++r) {
                float vv = acc[i][j][r] + bv;
                if (RELU) vv = fmaxf(vv, 0.f);
                if (nok) {
                    size_t idx = (size_t)(m0r + r) * ldc + n;
                    if (OUTF32) ((float*)Cv)[idx] = vv;
                    else        ((u16*)Cv)[idx] = f2bf(vv);
                }
            }
        }
    }
}

// ============================ launch ============================
extern "C" void kernel_launch(void* const* d_in, const int* in_sizes, int n_in,
                              void* d_out, int out_size, void* d_ws, size_t ws_size,
                              hipStream_t stream)
{
    const float* x    = (const float*)d_in[0];
    const float* Wih1 = (const float*)d_in[1];
    const float* Whh1 = (const float*)d_in[2];
    const float* bih1 = (const float*)d_in[3];
    const float* bhh1 = (const float*)d_in[4];
    const float* Wih2 = (const float*)d_in[5];
    const float* Whh2 = (const float*)d_in[6];
    const float* bih2 = (const float*)d_in[7];
    const float* bhh2 = (const float*)d_in[8];
    const float* Wih3 = (const float*)d_in[9];
    const float* Whh3 = (const float*)d_in[10];
    const float* bih3 = (const float*)d_in[11];
    const float* bhh3 = (const float*)d_in[12];
    const float* W1 = (const float*)d_in[13];
    const float* b1 = (const float*)d_in[14];
    const float* W2 = (const float*)d_in[15];
    const float* b2 = (const float*)d_in[16];
    const float* W3 = (const float*)d_in[17];
    const float* b3 = (const float*)d_in[18];

    // ws layout (bf16 elems): A1[2048][4896], A2[2048][4096], A3[2048][1024],
    // W1b[4096][4896] (K-padded), W2b[1024][4096], W3b[640][1024] (row-padded). ~91 MB.
    u16* A1  = (u16*)d_ws;
    u16* A2  = A1  + (size_t)2048 * K1P;
    u16* A3  = A2  + (size_t)2048 * 4096;
    u16* W1b = A3  + (size_t)2048 * 1024;
    u16* W2b = W1b + (size_t)4096 * K1P;
    u16* W3b = W2b + (size_t)1024 * 4096;

    // LSTM (blocks 0..1023) + fused weight conversions (blocks 1024..1279)
    lstm3_fused<<<1280, 192, 0, stream>>>(x, Wih1, Whh1, bih1, bhh1,
                                          Wih2, Whh2, bih2, bhh2,
                                          Wih3, Whh3, bih3, bhh3, A1,
                                          W1, W1b, W2, W2b, W3, W3b);

    // L1: [2048,4896] x W1b[4096,4896] -> relu -> A2 [2048,4096]  (bf16 out)
    gemm_bt<128, 128, true, false, false><<<dim3(32, 16), 256, 0, stream>>>(
        A1, K1P, W1b, K1P, b1, A2, 4096, 4096, K1P);

    // L2: [2048,4096] x W2b[1024,4096] -> relu -> A3 [2048,1024]  (bf16 out)
    gemm_bt<64, 128, true, false, false><<<dim3(8, 32), 256, 0, stream>>>(
        A2, 4096, W2b, 4096, b2, A3, 1024, 1024, 4096);

    // L3: [2048,1024] x W3b[640,1024] -> d_out [2048,609]  (fp32 out, store N-guard)
    gemm_bt<64, 128, false, true, true><<<dim3(5, 32), 256, 0, stream>>>(
        A3, 1024, W3b, 1024, b3, d_out, T_SZ, T_SZ, 1024);
}